// Round 6
// baseline (257.875 us; speedup 1.0000x reference)
//
#include <hip/hip_runtime.h>

// CARAFE++ (B=4, C=256, H=W=64, SCALE=2, K=5, G=1, MID=64, ENC_OUT=100). FP32 I/O.
// R11: 188.6us; enc 50.3us @ 52% VALU / ~52% LDS-pipe (both ~26us in a 50us
//   window). Non-enc residual ~138us: gather modeled at ~31us LDS-pipe
//   (3.28M wave-ds_reads, xv feeds only 2 FMAs), compress at ~20us (4x x
//   re-read, 4K wave-reads/CU).
// R12: raise FMA-per-ds_read in gather (all 4 p per thread: w[25][4],
//   400 wave-reads/block, float4 out) and halve compress traffic (m-half
//   split: grid 512, acc[8], s_load_dwordx8, x re-read 4x->2x). enc untouched.
//
// ws layout (float offsets):
#define OFF_FEAT 0              // feat [b][m][4096]               1,048,576 f
#define OFF_WET  1048576        // W_enc^T [m*9+rs][p*32+kk]          73,728 f
#define OFF_WCT  1122304        // W_comp^T [c][m]                    16,384 f
#define OFF_WK   1138688        // wk2 [p*25+k][b*4096+pix]        1,638,400 f
#define WS_FLOATS 2777088       // = 11,108,352 bytes

// ---------------- prep: weight transposes ----------------
__global__ __launch_bounds__(256) void prep_kernel(
    const float* __restrict__ Wc, const float* __restrict__ We,
    float* __restrict__ ws) {
    int i = blockIdx.x * 256 + threadIdx.x;
    if (i < 16384) {                       // WcT[c*64+m] = Wc[m][c]
        int c = i >> 6, m = i & 63;
        ws[OFF_WCT + i] = Wc[m * 256 + c];
    }
    if (i < 73728) {                       // Wet[(m*9+rs)*128 + p*32 + kk]
        int mrs = i >> 7, rem = i & 127;
        int p = rem >> 5, kk = rem & 31;
        ws[OFF_WET + i] = (kk < 25) ? We[(p * 25 + kk) * 576 + mrs] : 0.f;
    }
}

// ---------------- K1: 1x1 compress conv + relu ----------------
// grid 512 = 256 px-groups x 2 m-halves. 256 thr = 64 lanes x 4 chunks(8 m).
// x re-read 2x (was 4x); per c: 1 ds_read + 8 FMA (s_load_dwordx8 weights).
__global__ __launch_bounds__(256) void compress_kernel(
    const float* __restrict__ x, const float* __restrict__ bc,
    const float* __restrict__ ws, float* __restrict__ feat) {
    __shared__ float xs[64 * 64];          // 16 KB
    int blk = blockIdx.x;
    int pxg = blk >> 1, mh = blk & 1;
    int pixbase = pxg * 64;
    int b = pixbase >> 12, pl = pixbase & 4095;
    int lane = threadIdx.x & 63;
    int chunk = __builtin_amdgcn_readfirstlane(threadIdx.x >> 6);
    int m0 = mh * 32 + chunk * 8;          // wave-uniform, 32B-aligned weights
    const float* wct = ws + OFF_WCT;
    float acc[8];
#pragma unroll
    for (int q = 0; q < 8; q++) acc[q] = 0.f;
    for (int h = 0; h < 4; h++) {
        int ch0 = h << 6;
        for (int idx = threadIdx.x; idx < 64 * 64; idx += 256) {
            int c = idx >> 6, pp = idx & 63;
            xs[idx] = x[((b * 256 + ch0 + c) << 12) + pl + pp];
        }
        __syncthreads();
        for (int c = 0; c < 64; c++) {
            float xv = xs[(c << 6) + lane];
            const float* wr = wct + (ch0 + c) * 64 + m0;   // uniform -> s_load_dwordx8
#pragma unroll
            for (int q = 0; q < 8; q++) acc[q] += xv * wr[q];
        }
        __syncthreads();
    }
#pragma unroll
    for (int q = 0; q < 8; q++) {
        int m = m0 + q;
        float v = acc[q] + bc[m];
        feat[(b * 64 + m) * 4096 + pl + lane] = v > 0.f ? v : 0.f;
    }
}

// ---------------- K2: 3x3 enc conv + bias + softmax(25) ----------------
// grid 512 = (b x 8x8 tile) x 2 p-pairs. 512 thr = 64 px x (2p x 4 kg), q=8.
// Two-phase 32-m halo staging; LDS 16.9KB -> 2 blocks/CU = 16 waves/CU in two
// independent barrier domains. Weights: 1x s_load_dwordx8 per rs.
__global__ __launch_bounds__(512, 4) void enc_kernel(
    const float* __restrict__ be, const float* __restrict__ ws,
    float* __restrict__ wkout) {
    __shared__ float fs[4224];             // halo [32m][10][12]=3840 / logits [64px][2][33]
    int t = threadIdx.x;
    int blk = blockIdx.x;
    int tile = blk >> 1, ph2 = blk & 1;    // p-pair index
    int b = tile >> 6, t6 = tile & 63;
    int i0 = (t6 >> 3) << 3, j0 = (t6 & 7) << 3;
    int pix = t & 63;
    int li = pix >> 3, lj = pix & 7;
    int g = __builtin_amdgcn_readfirstlane(t >> 6);  // 0..7, wave-uniform
    int pp = g >> 2;                                 // p within pair
    int p = (ph2 << 1) | pp;
    int k0 = (g & 3) << 3;                           // kk = k0 + q, q<8 (pad >=25)
    const float* feat = ws + OFF_FEAT;
    const float* wet = ws + OFF_WET + p * 32 + k0;   // uniform, 32B-aligned

    float acc[8];
#pragma unroll
    for (int q = 0; q < 8; q++) acc[q] = 0.f;

    for (int phase = 0; phase < 2; phase++) {
        int mb = phase << 5;
        for (int idx = t; idx < 3200; idx += 512) {  // stage 32-m halo (0-padded)
            int m = idx / 100, pos = idx - m * 100;
            int r = pos / 10, s = pos - r * 10;
            int gi = i0 + r - 1, gj = j0 + s - 1;
            float v = 0.f;
            if ((unsigned)gi < 64u && (unsigned)gj < 64u)
                v = feat[(b * 64 + mb + m) * 4096 + (gi << 6) + gj];
            fs[m * 120 + r * 12 + s] = v;            // stride-12 rows (2-way = free)
        }
        __syncthreads();

#pragma unroll 2
        for (int m = 0; m < 32; m++) {
            const float* fb = fs + m * 120 + li * 12 + lj;
            float f9[9];
#pragma unroll
            for (int r = 0; r < 3; r++)
#pragma unroll
                for (int s = 0; s < 3; s++) f9[r * 3 + s] = fb[r * 12 + s];
            const float* wrow = wet + (mb + m) * 1152;   // uniform -> s_load_dwordx8
#pragma unroll
            for (int rs = 0; rs < 9; rs++) {
                float f = f9[rs];
                const float* wr = wrow + rs * 128;
#pragma unroll
                for (int q = 0; q < 8; q++) acc[q] += f * wr[q];
            }
        }
        __syncthreads();                             // reads done before re-stage
    }

    // logits (+bias) -> fs[pix*66 + pp*33 + kk] (kk>=25 pad skipped)
#pragma unroll
    for (int q = 0; q < 8; q++) {
        int k = k0 + q;
        if (k < 25) fs[pix * 66 + pp * 33 + k] = acc[q] + be[p * 25 + k];
    }
    __syncthreads();

    if (t < 128) {                                   // softmax: thread = (pp, pixel)
        int sp = t >> 6, spx = t & 63;
        const float* lg = fs + spx * 66 + sp * 33;
        float sv[25], mx = -1e30f;
#pragma unroll
        for (int k = 0; k < 25; k++) { sv[k] = lg[k]; mx = fmaxf(mx, sv[k]); }
        float s = 0.f;
#pragma unroll
        for (int k = 0; k < 25; k++) { sv[k] = __expf(sv[k] - mx); s += sv[k]; }
        float inv = 1.f / s;
        int preal = (ph2 << 1) | sp;
        int pgl = ((i0 + (spx >> 3)) << 6) + j0 + (spx & 7);
        float* wp = wkout + (preal * 25) * 16384 + (b << 12) + pgl;
#pragma unroll
        for (int k = 0; k < 25; k++) wp[k * 16384] = sv[k] * inv;  // coalesced
    }
}

// ---------------- K3: gather + pixel rearrange ----------------
// grid 4096 = (b*64+i)*16 + cc(16 ch). 256 thr = 64 j x 4 c-groups (4 c each).
// Each thread computes ALL 4 p per xv read (w[25][4] in VGPR): block wave-reads
// 800 -> 400; output is one coalesced float4 per (c,pixel).
__global__ __launch_bounds__(256) void gather_kernel(
    const float* __restrict__ x, const float* __restrict__ ws,
    float* __restrict__ out) {
    __shared__ float xs[16 * 5 * 68];                // 21.76 KB
    int t = threadIdx.x;
    int blk = blockIdx.x;
    int cc = blk & 15;
    int bi = blk >> 4;
    int b = bi >> 6, i = bi & 63;
    int j = t & 63;
    int g = t >> 6;                                  // c-group 0..3

    // coalesced wk loads: wk2[(p*25+k)*16384 + b*4096 + i*64 + j]
    float w[25][4];
    {
        const float* wp = ws + OFF_WK + (b << 12) + (i << 6) + j;
#pragma unroll
        for (int p = 0; p < 4; p++)
#pragma unroll
            for (int k = 0; k < 25; k++)
                w[k][p] = wp[(p * 25 + k) * 16384];
    }

    // div-free-ish staging: aligned 64-float row core + guarded zero pads.
    {
        int lane = t & 63, cd0 = t >> 6;             // (c,dy) pairs, 4 at a time
        for (int cd = cd0; cd < 80; cd += 4) {
            int c = cd / 5, dy = cd - c * 5;
            int gi = i - 2 + dy;
            float v = 0.f;
            if ((unsigned)gi < 64u)
                v = x[((b * 256 + (cc << 4) + c) << 12) + (gi << 6) + lane];
            float* row = xs + cd * 68;
            row[2 + lane] = v;
            if (lane < 2) row[lane] = 0.f;           // gj < 0 pad
            if (lane >= 62) row[lane + 4] = 0.f;     // gj >= 64 pad
        }
    }
    __syncthreads();

#pragma unroll
    for (int cq = 0; cq < 4; cq++) {
        int c2 = (g << 2) + cq;
        const float* xb = xs + (c2 * 5) * 68 + j;    // u = j+dx -> gj = j+dx-2
        float a0 = 0.f, a1 = 0.f, a2 = 0.f, a3 = 0.f;
#pragma unroll
        for (int dy = 0; dy < 5; dy++) {
#pragma unroll
            for (int dx = 0; dx < 5; dx++) {
                float xv = xb[dy * 68 + dx];
                int k = dy * 5 + dx;
                a0 += xv * w[k][0];
                a1 += xv * w[k][1];
                a2 += xv * w[k][2];
                a3 += xv * w[k][3];
            }
        }
        int c = (cc << 4) + c2;
        float4 o4 = make_float4(a0, a1, a2, a3);
        *(float4*)(out + (((b * 256 + c) << 12) + (i << 6) + j) * 4) = o4;
    }
}

// ---------------- fallback: round-3 fused kernel (correct, slow) ----------------
__global__ __launch_bounds__(512) void carafe_fused(
    const float* __restrict__ x, const float* __restrict__ Wc,
    const float* __restrict__ bc, const float* __restrict__ We,
    const float* __restrict__ be, float* __restrict__ out) {
    __shared__ float xs[32 * 144];
    __shared__ float fw[6656];
    __shared__ float wst[3600];
    const int t = threadIdx.x;
    const int blk = blockIdx.x;
    const int b = blk >> 6, tile = blk & 63;
    const int i0 = (tile >> 3) << 3, j0 = (tile & 7) << 3;
    const int wid = t >> 6, pix = t & 63;
    const int li = pix >> 3, lj = pix & 7;
    float facc[13];
#pragma unroll
    for (int q = 0; q < 13; q++) facc[q] = 0.f;
    for (int cc = 0; cc < 8; cc++) {
        for (int idx = t; idx < 32 * 144; idx += 512) {
            int c = idx / 144, pos = idx - c * 144;
            int r = pos / 12, u = pos - r * 12;
            int gi = i0 + r - 2, gj = j0 + u - 2;
            float v = 0.f;
            if ((unsigned)gi < 64u && (unsigned)gj < 64u)
                v = x[(((b * 256 + cc * 32 + c) << 12) + (gi << 6) + gj)];
            xs[idx] = v;
        }
        __syncthreads();
#pragma unroll
        for (int q = 0; q < 13; q++) {
            int idx = q * 512 + t;
            if (idx < 6400) {
                int m = idx / 100, pos = idx - m * 100;
                int fi = pos / 10, fj = pos - fi * 10;
                int tp = (fi + 1) * 12 + fj + 1;
                const float* wr = Wc + m * 256 + cc * 32;
                float a = facc[q];
                for (int c = 0; c < 32; c++) a += xs[c * 144 + tp] * wr[c];
                facc[q] = a;
            }
        }
        __syncthreads();
    }
#pragma unroll
    for (int q = 0; q < 13; q++) {
        int idx = q * 512 + t;
        if (idx < 6400) {
            int m = idx / 100, pos = idx - m * 100;
            int fi = pos / 10, fj = pos - fi * 10;
            int gi = i0 + fi - 1, gj = j0 + fj - 1;
            float v = facc[q] + bc[m];
            v = v > 0.f ? v : 0.f;
            if ((unsigned)gi >= 64u || (unsigned)gj >= 64u) v = 0.f;
            fw[idx] = v;
        }
    }
    float acc[13];
#pragma unroll
    for (int q = 0; q < 13; q++) acc[q] = 0.f;
    for (int mb = 0; mb < 16; mb++) {
        for (int idx = t; idx < 3600; idx += 512) {
            int mm = idx / 900, rem = idx - mm * 900;
            int o = rem / 9, rs = rem - o * 9;
            wst[idx] = We[o * 576 + (mb * 4 + mm) * 9 + rs];
        }
        __syncthreads();
#pragma unroll
        for (int mm = 0; mm < 4; mm++) {
            const float* fb = fw + (mb * 4 + mm) * 100 + li * 10 + lj;
            float f9[9];
#pragma unroll
            for (int r = 0; r < 3; r++)
#pragma unroll
                for (int s = 0; s < 3; s++) f9[r * 3 + s] = fb[r * 10 + s];
#pragma unroll
            for (int q = 0; q < 13; q++) {
                int o = q * 8 + wid;
                if (o < 100) {
                    const float* wr = wst + mm * 900 + o * 9;
                    float a = acc[q];
#pragma unroll
                    for (int rs = 0; rs < 9; rs++) a += f9[rs] * wr[rs];
                    acc[q] = a;
                }
            }
        }
        __syncthreads();
    }
#pragma unroll
    for (int q = 0; q < 13; q++) {
        int o = q * 8 + wid;
        if (o < 100) fw[pix * 104 + o] = acc[q];
    }
    __syncthreads();
    float sv[25];
    float inv = 0.f;
    const int sp = t >> 6, spx = t & 63;
    const bool act = (t < 256);
    if (act) {
        float mx = -1e30f;
#pragma unroll
        for (int k = 0; k < 25; k++) {
            sv[k] = fw[spx * 104 + sp * 25 + k] + be[sp * 25 + k];
            mx = fmaxf(mx, sv[k]);
        }
        float s = 0.f;
#pragma unroll
        for (int k = 0; k < 25; k++) { sv[k] = __expf(sv[k] - mx); s += sv[k]; }
        inv = 1.f / s;
    }
    __syncthreads();
    if (act) {
#pragma unroll
        for (int k = 0; k < 25; k++) fw[spx * 104 + k * 4 + sp] = sv[k] * inv;
    }
    __syncthreads();
    float w[25][4];
    const float4* wp = (const float4*)(fw + pix * 104);
#pragma unroll
    for (int k = 0; k < 25; k++) {
        float4 ww = wp[k];
        w[k][0] = ww.x; w[k][1] = ww.y; w[k][2] = ww.z; w[k][3] = ww.w;
    }
    const int pgl = ((i0 + li) << 6) + (j0 + lj);
    for (int cc = 0; cc < 8; cc++) {
        for (int idx = t; idx < 32 * 144; idx += 512) {
            int c = idx / 144, pos = idx - c * 144;
            int r = pos / 12, u = pos - r * 12;
            int gi = i0 + r - 2, gj = j0 + u - 2;
            float v = 0.f;
            if ((unsigned)gi < 64u && (unsigned)gj < 64u)
                v = x[(((b * 256 + cc * 32 + c) << 12) + (gi << 6) + gj)];
            xs[idx] = v;
        }
        __syncthreads();
        for (int c8 = wid; c8 < 32; c8 += 8) {
            const float* xc = xs + c8 * 144 + li * 12 + lj;
            float a0 = 0.f, a1 = 0.f, a2 = 0.f, a3 = 0.f;
#pragma unroll
            for (int dy = 0; dy < 5; dy++) {
#pragma unroll
                for (int dx = 0; dx < 5; dx++) {
                    float xv = xc[dy * 12 + dx];
                    const int k = dy * 5 + dx;
                    a0 += xv * w[k][0];
                    a1 += xv * w[k][1];
                    a2 += xv * w[k][2];
                    a3 += xv * w[k][3];
                }
            }
            int c = cc * 32 + c8;
            float4 o4 = make_float4(a0, a1, a2, a3);
            *(float4*)(out + (((long long)(b * 256 + c)) << 14) + pgl * 4) = o4;
        }
        __syncthreads();
    }
}

extern "C" void kernel_launch(void* const* d_in, const int* in_sizes, int n_in,
                              void* d_out, int out_size, void* d_ws, size_t ws_size,
                              hipStream_t stream) {
    const float* x  = (const float*)d_in[0];
    const float* Wc = (const float*)d_in[1];
    const float* bc = (const float*)d_in[2];
    const float* We = (const float*)d_in[3];
    const float* be = (const float*)d_in[4];
    float* out = (float*)d_out;

    if (ws_size >= (size_t)WS_FLOATS * sizeof(float)) {
        float* ws = (float*)d_ws;
        prep_kernel<<<288, 256, 0, stream>>>(Wc, We, ws);
        compress_kernel<<<512, 256, 0, stream>>>(x, bc, ws, ws + OFF_FEAT);
        enc_kernel<<<512, 512, 0, stream>>>(be, ws, ws + OFF_WK);
        gather_kernel<<<4096, 256, 0, stream>>>(x, ws, out);
    } else {
        carafe_fused<<<256, 512, 0, stream>>>(x, Wc, bc, We, be, out);
    }
}

// Round 7
// 220.826 us; speedup vs baseline: 1.1678x; 1.1678x over previous
//
#include <hip/hip_runtime.h>

// CARAFE++ (B=4, C=256, H=W=64, SCALE=2, K=5, G=1, MID=64, ENC_OUT=100). FP32 I/O.
// R12: 257.9us REGRESSION (compress 77us @ VGPR 116, 8 waves/CU, VALU 17.9%;
//   gather w[25][4]=100 VGPR also slid ~+30). Lesson: latency-bound kernels —
//   never trade waves for per-thread state. FETCH 17MB << x's 67MB -> x is
//   L3-resident; HBM irrelevant, pipes+latency rule.
// R13: gather reverted to R11 (known ~40-45us). enc kept (50.3us best).
//   compress redesigned: NO LDS, thread=pixel, acc[32] (one m-half),
//   weights via uniform s_load_dwordx16, x streamed coalesced from L3.
//   grid 128 = 64 pxg(256px) x 2 mh. Per-block crit path 256c x 64cyc = 6.8us.
//
// ws layout (float offsets):
#define OFF_FEAT 0              // feat [b][m][4096]               1,048,576 f
#define OFF_WET  1048576        // W_enc^T [m*9+rs][p*32+kk]          73,728 f
#define OFF_WCT  1122304        // W_comp^T [c][m]                    16,384 f
#define OFF_WK   1138688        // wk2 [p*25+k][b*4096+pix]        1,638,400 f
#define WS_FLOATS 2777088       // = 11,108,352 bytes

// ---------------- prep: weight transposes ----------------
__global__ __launch_bounds__(256) void prep_kernel(
    const float* __restrict__ Wc, const float* __restrict__ We,
    float* __restrict__ ws) {
    int i = blockIdx.x * 256 + threadIdx.x;
    if (i < 16384) {                       // WcT[c*64+m] = Wc[m][c]
        int c = i >> 6, m = i & 63;
        ws[OFF_WCT + i] = Wc[m * 256 + c];
    }
    if (i < 73728) {                       // Wet[(m*9+rs)*128 + p*32 + kk]
        int mrs = i >> 7, rem = i & 127;
        int p = rem >> 5, kk = rem & 31;
        ws[OFF_WET + i] = (kk < 25) ? We[(p * 25 + kk) * 576 + mrs] : 0.f;
    }
}

// ---------------- K1: 1x1 compress conv + relu ----------------
// grid 128 = 64 px-groups(256 px) x 2 m-halves. 256 thr = 1 px each.
// No LDS, no barriers: x streamed coalesced (L3-hot), weights s_load_dwordx16,
// 32 FMA per load -> 64 cyc of VALU per x element; unroll 4 pipelines loads.
__global__ __launch_bounds__(256) void compress_kernel(
    const float* __restrict__ x, const float* __restrict__ bc,
    const float* __restrict__ ws, float* __restrict__ feat) {
    int blk = blockIdx.x;
    int pxg = blk >> 1, mh = blk & 1;
    int pixbase = pxg << 8;
    int b = pixbase >> 12, pl = pixbase & 4095;
    int t = threadIdx.x;
    const float* wct = ws + OFF_WCT + mh * 32;       // uniform -> s_load
    const float* xp = x + (((long long)b * 256) << 12) + pl + t;
    float acc[32];
#pragma unroll
    for (int q = 0; q < 32; q++) acc[q] = 0.f;
#pragma unroll 4
    for (int c = 0; c < 256; c++) {
        float xv = xp[(size_t)c << 12];
        const float* wr = wct + (c << 6);            // 32 consecutive m: 2x dwordx16
#pragma unroll
        for (int q = 0; q < 32; q++) acc[q] += xv * wr[q];
    }
    int m0 = mh << 5;
#pragma unroll
    for (int q = 0; q < 32; q++) {
        float v = acc[q] + bc[m0 + q];
        feat[((b * 64 + m0 + q) << 12) + pl + t] = v > 0.f ? v : 0.f;
    }
}

// ---------------- K2: 3x3 enc conv + bias + softmax(25) ----------------
// grid 512 = (b x 8x8 tile) x 2 p-pairs. 512 thr = 64 px x (2p x 4 kg), q=8.
// Two-phase 32-m halo staging; LDS 16.9KB -> 2 blocks/CU = 16 waves/CU in two
// independent barrier domains. Weights: 1x s_load_dwordx8 per rs.
__global__ __launch_bounds__(512, 4) void enc_kernel(
    const float* __restrict__ be, const float* __restrict__ ws,
    float* __restrict__ wkout) {
    __shared__ float fs[4224];             // halo [32m][10][12]=3840 / logits [64px][2][33]
    int t = threadIdx.x;
    int blk = blockIdx.x;
    int tile = blk >> 1, ph2 = blk & 1;    // p-pair index
    int b = tile >> 6, t6 = tile & 63;
    int i0 = (t6 >> 3) << 3, j0 = (t6 & 7) << 3;
    int pix = t & 63;
    int li = pix >> 3, lj = pix & 7;
    int g = __builtin_amdgcn_readfirstlane(t >> 6);  // 0..7, wave-uniform
    int pp = g >> 2;                                 // p within pair
    int p = (ph2 << 1) | pp;
    int k0 = (g & 3) << 3;                           // kk = k0 + q, q<8 (pad >=25)
    const float* feat = ws + OFF_FEAT;
    const float* wet = ws + OFF_WET + p * 32 + k0;   // uniform, 32B-aligned

    float acc[8];
#pragma unroll
    for (int q = 0; q < 8; q++) acc[q] = 0.f;

    for (int phase = 0; phase < 2; phase++) {
        int mb = phase << 5;
        for (int idx = t; idx < 3200; idx += 512) {  // stage 32-m halo (0-padded)
            int m = idx / 100, pos = idx - m * 100;
            int r = pos / 10, s = pos - r * 10;
            int gi = i0 + r - 1, gj = j0 + s - 1;
            float v = 0.f;
            if ((unsigned)gi < 64u && (unsigned)gj < 64u)
                v = feat[(b * 64 + mb + m) * 4096 + (gi << 6) + gj];
            fs[m * 120 + r * 12 + s] = v;            // stride-12 rows (2-way = free)
        }
        __syncthreads();

#pragma unroll 2
        for (int m = 0; m < 32; m++) {
            const float* fb = fs + m * 120 + li * 12 + lj;
            float f9[9];
#pragma unroll
            for (int r = 0; r < 3; r++)
#pragma unroll
                for (int s = 0; s < 3; s++) f9[r * 3 + s] = fb[r * 12 + s];
            const float* wrow = wet + (mb + m) * 1152;   // uniform -> s_load_dwordx8
#pragma unroll
            for (int rs = 0; rs < 9; rs++) {
                float f = f9[rs];
                const float* wr = wrow + rs * 128;
#pragma unroll
                for (int q = 0; q < 8; q++) acc[q] += f * wr[q];
            }
        }
        __syncthreads();                             // reads done before re-stage
    }

    // logits (+bias) -> fs[pix*66 + pp*33 + kk] (kk>=25 pad skipped)
#pragma unroll
    for (int q = 0; q < 8; q++) {
        int k = k0 + q;
        if (k < 25) fs[pix * 66 + pp * 33 + k] = acc[q] + be[p * 25 + k];
    }
    __syncthreads();

    if (t < 128) {                                   // softmax: thread = (pp, pixel)
        int sp = t >> 6, spx = t & 63;
        const float* lg = fs + spx * 66 + sp * 33;
        float sv[25], mx = -1e30f;
#pragma unroll
        for (int k = 0; k < 25; k++) { sv[k] = lg[k]; mx = fmaxf(mx, sv[k]); }
        float s = 0.f;
#pragma unroll
        for (int k = 0; k < 25; k++) { sv[k] = __expf(sv[k] - mx); s += sv[k]; }
        float inv = 1.f / s;
        int preal = (ph2 << 1) | sp;
        int pgl = ((i0 + (spx >> 3)) << 6) + j0 + (spx & 7);
        float* wp = wkout + (preal * 25) * 16384 + (b << 12) + pgl;
#pragma unroll
        for (int k = 0; k < 25; k++) wp[k * 16384] = sv[k] * inv;  // coalesced
    }
}

// ---------------- K3: gather + pixel rearrange ----------------
// grid 4096 = (b*64+i)*16 + cc(16 ch). 256 thr = 64 j x (2 p-pairs x 2 c-halves).
__global__ __launch_bounds__(256) void gather_kernel(
    const float* __restrict__ x, const float* __restrict__ ws,
    float* __restrict__ out) {
    __shared__ float xs[16 * 5 * 68];                // 21.76 KB
    int t = threadIdx.x;
    int blk = blockIdx.x;
    int cc = blk & 15;
    int bi = blk >> 4;
    int b = bi >> 6, i = bi & 63;
    int j = t & 63;
    int g = t >> 6;
    int ph = g >> 1, ch = g & 1;

    // coalesced wk loads: wk2[(p*25+k)*16384 + b*4096 + i*64 + j]
    float w0[25], w1[25];
    {
        const float* wp = ws + OFF_WK + (ph * 50) * 16384 + (b << 12) + (i << 6) + j;
#pragma unroll
        for (int k = 0; k < 25; k++) {
            w0[k] = wp[k * 16384];
            w1[k] = wp[(25 + k) * 16384];
        }
    }

    // div-free-ish staging: aligned 64-float row core + guarded zero pads.
    {
        int lane = t & 63, cd0 = t >> 6;             // (c,dy) pairs, 4 at a time
        for (int cd = cd0; cd < 80; cd += 4) {
            int c = cd / 5, dy = cd - c * 5;
            int gi = i - 2 + dy;
            float v = 0.f;
            if ((unsigned)gi < 64u)
                v = x[((b * 256 + (cc << 4) + c) << 12) + (gi << 6) + lane];
            float* row = xs + cd * 68;
            row[2 + lane] = v;
            if (lane < 2) row[lane] = 0.f;           // gj < 0 pad
            if (lane >= 62) row[lane + 4] = 0.f;     // gj >= 64 pad
        }
    }
    __syncthreads();

    for (int c2 = ch; c2 < 16; c2 += 2) {
        const float* xb = xs + (c2 * 5) * 68 + j;    // u = j+dx -> gj = j+dx-2
        float a0 = 0.f, a1 = 0.f;
#pragma unroll
        for (int dy = 0; dy < 5; dy++) {
#pragma unroll
            for (int dx = 0; dx < 5; dx++) {
                float xv = xb[dy * 68 + dx];
                int k = dy * 5 + dx;
                a0 += xv * w0[k];
                a1 += xv * w1[k];
            }
        }
        int c = (cc << 4) + c2;
        float2 o2 = make_float2(a0, a1);
        *(float2*)(out + (((b * 256 + c) << 12) + (i << 6) + j) * 4 + ph * 2) = o2;
    }
}

// ---------------- fallback: round-3 fused kernel (correct, slow) ----------------
__global__ __launch_bounds__(512) void carafe_fused(
    const float* __restrict__ x, const float* __restrict__ Wc,
    const float* __restrict__ bc, const float* __restrict__ We,
    const float* __restrict__ be, float* __restrict__ out) {
    __shared__ float xs[32 * 144];
    __shared__ float fw[6656];
    __shared__ float wst[3600];
    const int t = threadIdx.x;
    const int blk = blockIdx.x;
    const int b = blk >> 6, tile = blk & 63;
    const int i0 = (tile >> 3) << 3, j0 = (tile & 7) << 3;
    const int wid = t >> 6, pix = t & 63;
    const int li = pix >> 3, lj = pix & 7;
    float facc[13];
#pragma unroll
    for (int q = 0; q < 13; q++) facc[q] = 0.f;
    for (int cc = 0; cc < 8; cc++) {
        for (int idx = t; idx < 32 * 144; idx += 512) {
            int c = idx / 144, pos = idx - c * 144;
            int r = pos / 12, u = pos - r * 12;
            int gi = i0 + r - 2, gj = j0 + u - 2;
            float v = 0.f;
            if ((unsigned)gi < 64u && (unsigned)gj < 64u)
                v = x[(((b * 256 + cc * 32 + c) << 12) + (gi << 6) + gj)];
            xs[idx] = v;
        }
        __syncthreads();
#pragma unroll
        for (int q = 0; q < 13; q++) {
            int idx = q * 512 + t;
            if (idx < 6400) {
                int m = idx / 100, pos = idx - m * 100;
                int fi = pos / 10, fj = pos - fi * 10;
                int tp = (fi + 1) * 12 + fj + 1;
                const float* wr = Wc + m * 256 + cc * 32;
                float a = facc[q];
                for (int c = 0; c < 32; c++) a += xs[c * 144 + tp] * wr[c];
                facc[q] = a;
            }
        }
        __syncthreads();
    }
#pragma unroll
    for (int q = 0; q < 13; q++) {
        int idx = q * 512 + t;
        if (idx < 6400) {
            int m = idx / 100, pos = idx - m * 100;
            int fi = pos / 10, fj = pos - fi * 10;
            int gi = i0 + fi - 1, gj = j0 + fj - 1;
            float v = facc[q] + bc[m];
            v = v > 0.f ? v : 0.f;
            if ((unsigned)gi >= 64u || (unsigned)gj >= 64u) v = 0.f;
            fw[idx] = v;
        }
    }
    float acc[13];
#pragma unroll
    for (int q = 0; q < 13; q++) acc[q] = 0.f;
    for (int mb = 0; mb < 16; mb++) {
        for (int idx = t; idx < 3600; idx += 512) {
            int mm = idx / 900, rem = idx - mm * 900;
            int o = rem / 9, rs = rem - o * 9;
            wst[idx] = We[o * 576 + (mb * 4 + mm) * 9 + rs];
        }
        __syncthreads();
#pragma unroll
        for (int mm = 0; mm < 4; mm++) {
            const float* fb = fw + (mb * 4 + mm) * 100 + li * 10 + lj;
            float f9[9];
#pragma unroll
            for (int r = 0; r < 3; r++)
#pragma unroll
                for (int s = 0; s < 3; s++) f9[r * 3 + s] = fb[r * 10 + s];
#pragma unroll
            for (int q = 0; q < 13; q++) {
                int o = q * 8 + wid;
                if (o < 100) {
                    const float* wr = wst + mm * 900 + o * 9;
                    float a = acc[q];
#pragma unroll
                    for (int rs = 0; rs < 9; rs++) a += f9[rs] * wr[rs];
                    acc[q] = a;
                }
            }
        }
        __syncthreads();
    }
#pragma unroll
    for (int q = 0; q < 13; q++) {
        int o = q * 8 + wid;
        if (o < 100) fw[pix * 104 + o] = acc[q];
    }
    __syncthreads();
    float sv[25];
    float inv = 0.f;
    const int sp = t >> 6, spx = t & 63;
    const bool act = (t < 256);
    if (act) {
        float mx = -1e30f;
#pragma unroll
        for (int k = 0; k < 25; k++) {
            sv[k] = fw[spx * 104 + sp * 25 + k] + be[sp * 25 + k];
            mx = fmaxf(mx, sv[k]);
        }
        float s = 0.f;
#pragma unroll
        for (int k = 0; k < 25; k++) { sv[k] = __expf(sv[k] - mx); s += sv[k]; }
        inv = 1.f / s;
    }
    __syncthreads();
    if (act) {
#pragma unroll
        for (int k = 0; k < 25; k++) fw[spx * 104 + k * 4 + sp] = sv[k] * inv;
    }
    __syncthreads();
    float w[25][4];
    const float4* wp = (const float4*)(fw + pix * 104);
#pragma unroll
    for (int k = 0; k < 25; k++) {
        float4 ww = wp[k];
        w[k][0] = ww.x; w[k][1] = ww.y; w[k][2] = ww.z; w[k][3] = ww.w;
    }
    const int pgl = ((i0 + li) << 6) + (j0 + lj);
    for (int cc = 0; cc < 8; cc++) {
        for (int idx = t; idx < 32 * 144; idx += 512) {
            int c = idx / 144, pos = idx - c * 144;
            int r = pos / 12, u = pos - r * 12;
            int gi = i0 + r - 2, gj = j0 + u - 2;
            float v = 0.f;
            if ((unsigned)gi < 64u && (unsigned)gj < 64u)
                v = x[(((b * 256 + cc * 32 + c) << 12) + (gi << 6) + gj)];
            xs[idx] = v;
        }
        __syncthreads();
        for (int c8 = wid; c8 < 32; c8 += 8) {
            const float* xc = xs + c8 * 144 + li * 12 + lj;
            float a0 = 0.f, a1 = 0.f, a2 = 0.f, a3 = 0.f;
#pragma unroll
            for (int dy = 0; dy < 5; dy++) {
#pragma unroll
                for (int dx = 0; dx < 5; dx++) {
                    float xv = xc[dy * 12 + dx];
                    const int k = dy * 5 + dx;
                    a0 += xv * w[k][0];
                    a1 += xv * w[k][1];
                    a2 += xv * w[k][2];
                    a3 += xv * w[k][3];
                }
            }
            int c = cc * 32 + c8;
            float4 o4 = make_float4(a0, a1, a2, a3);
            *(float4*)(out + (((long long)(b * 256 + c)) << 14) + pgl * 4) = o4;
        }
        __syncthreads();
    }
}

extern "C" void kernel_launch(void* const* d_in, const int* in_sizes, int n_in,
                              void* d_out, int out_size, void* d_ws, size_t ws_size,
                              hipStream_t stream) {
    const float* x  = (const float*)d_in[0];
    const float* Wc = (const float*)d_in[1];
    const float* bc = (const float*)d_in[2];
    const float* We = (const float*)d_in[3];
    const float* be = (const float*)d_in[4];
    float* out = (float*)d_out;

    if (ws_size >= (size_t)WS_FLOATS * sizeof(float)) {
        float* ws = (float*)d_ws;
        prep_kernel<<<288, 256, 0, stream>>>(Wc, We, ws);
        compress_kernel<<<128, 256, 0, stream>>>(x, bc, ws, ws + OFF_FEAT);
        enc_kernel<<<512, 512, 0, stream>>>(be, ws, ws + OFF_WK);
        gather_kernel<<<4096, 256, 0, stream>>>(x, ws, out);
    } else {
        carafe_fused<<<256, 512, 0, stream>>>(x, Wc, bc, We, be, out);
    }
}

// Round 8
// 194.287 us; speedup vs baseline: 1.3273x; 1.1366x over previous
//
#include <hip/hip_runtime.h>

// CARAFE++ (B=4, C=256, H=W=64, SCALE=2, K=5, G=1, MID=64, ENC_OUT=100). FP32 I/O.
// R13: 220.8us; compress 57us @ VALU 5.8%, occ 5.3%, VGPR 28 (!) with acc[32]
//   in source -> accumulators spilled to scratch + grid 128 = half GPU idle.
//   Recurring villain: per-c s_load weight chains + too few waves.
// R14: compress lane=m design: weight WcT[c*64+lane] is a coalesced per-lane
//   load (no s_load chain, 256 independent iters), x[b][c][px] is wave-uniform
//   (float4 broadcast -> SGPR operand, 4 FMAs each). acc[4], no LDS, NO
//   barriers, grid 1024x256 = 4 waves/SIMD. feat layout flips to [b][pix][m]
//   (compress writes coalesce over m); enc staging re-indexed to match,
//   fs row stride 120->121 keeps stage-writes conflict-free. gather = R11.
//
// ws layout (float offsets):
#define OFF_FEAT 0              // feat [b][pix][m=64]             1,048,576 f
#define OFF_WET  1048576        // W_enc^T [m*9+rs][p*32+kk]          73,728 f
#define OFF_WCT  1122304        // W_comp^T [c][m]                    16,384 f
#define OFF_WK   1138688        // wk2 [p*25+k][b*4096+pix]        1,638,400 f
#define WS_FLOATS 2777088       // = 11,108,352 bytes

// ---------------- prep: weight transposes ----------------
__global__ __launch_bounds__(256) void prep_kernel(
    const float* __restrict__ Wc, const float* __restrict__ We,
    float* __restrict__ ws) {
    int i = blockIdx.x * 256 + threadIdx.x;
    if (i < 16384) {                       // WcT[c*64+m] = Wc[m][c]
        int c = i >> 6, m = i & 63;
        ws[OFF_WCT + i] = Wc[m * 256 + c];
    }
    if (i < 73728) {                       // Wet[(m*9+rs)*128 + p*32 + kk]
        int mrs = i >> 7, rem = i & 127;
        int p = rem >> 5, kk = rem & 31;
        ws[OFF_WET + i] = (kk < 25) ? We[(p * 25 + kk) * 576 + mrs] : 0.f;
    }
}

// ---------------- K1: 1x1 compress conv + relu ----------------
// grid 1024 x 256 thr = 4 waves/block, wave = 4 px, lane = m.
// Per c: 1 coalesced w-load (VGPR) + 1 uniform float4 x-read (SGPR) + 4 FMA.
// No LDS, no barriers; acc[4] -> ~24 VGPR -> 4 blocks/CU, 4 waves/SIMD.
__global__ __launch_bounds__(256) void compress_kernel(
    const float* __restrict__ x, const float* __restrict__ bc,
    const float* __restrict__ ws, float* __restrict__ feat) {
    int t = threadIdx.x;
    int lane = t & 63;                               // = m
    int px0 = __builtin_amdgcn_readfirstlane((blockIdx.x << 4) + ((t >> 6) << 2));
    int b = px0 >> 12, pl = px0 & 4095;
    const float* wct = ws + OFF_WCT;                 // [c][64 m]
    const float* xw = x + (((size_t)(b * 256)) << 12) + pl;   // wave-uniform
    float acc0 = 0.f, acc1 = 0.f, acc2 = 0.f, acc3 = 0.f;
#pragma unroll 4
    for (int c = 0; c < 256; c++) {
        float w = wct[(c << 6) + lane];              // coalesced, L2-hot
        const float4 xv = *(const float4*)(xw + ((size_t)c << 12));  // uniform
        acc0 += xv.x * w;
        acc1 += xv.y * w;
        acc2 += xv.z * w;
        acc3 += xv.w * w;
    }
    float bv = bc[lane];
    float v0 = acc0 + bv, v1 = acc1 + bv, v2 = acc2 + bv, v3 = acc3 + bv;
    float* fp = feat + (((size_t)((b << 12) + pl)) << 6) + lane;  // [pix][m]
    fp[0]       = v0 > 0.f ? v0 : 0.f;               // coalesced over m
    fp[64]      = v1 > 0.f ? v1 : 0.f;
    fp[128]     = v2 > 0.f ? v2 : 0.f;
    fp[192]     = v3 > 0.f ? v3 : 0.f;
}

// ---------------- K2: 3x3 enc conv + bias + softmax(25) ----------------
// grid 512 = (b x 8x8 tile) x 2 p-pairs. 512 thr = 64 px x (2p x 4 kg), q=8.
// Two-phase 32-m halo staging from feat[pix][m] (coalesced over m);
// fs rows stride 121 (pad) -> conflict-free stage writes, 2-way reads (free).
__global__ __launch_bounds__(512, 4) void enc_kernel(
    const float* __restrict__ be, const float* __restrict__ ws,
    float* __restrict__ wkout) {
    __shared__ float fs[4224];             // halo [32m][121] / logits [64px][2][33]
    int t = threadIdx.x;
    int blk = blockIdx.x;
    int tile = blk >> 1, ph2 = blk & 1;    // p-pair index
    int b = tile >> 6, t6 = tile & 63;
    int i0 = (t6 >> 3) << 3, j0 = (t6 & 7) << 3;
    int pix = t & 63;
    int li = pix >> 3, lj = pix & 7;
    int g = __builtin_amdgcn_readfirstlane(t >> 6);  // 0..7, wave-uniform
    int pp = g >> 2;                                 // p within pair
    int p = (ph2 << 1) | pp;
    int k0 = (g & 3) << 3;                           // kk = k0 + q, q<8 (pad >=25)
    const float* feat = ws + OFF_FEAT;               // [b][pix][64 m]
    const float* wet = ws + OFF_WET + p * 32 + k0;   // uniform, 32B-aligned

    float acc[8];
#pragma unroll
    for (int q = 0; q < 8; q++) acc[q] = 0.f;

    for (int phase = 0; phase < 2; phase++) {
        int mb = phase << 5;
        for (int idx = t; idx < 3200; idx += 512) {  // stage 32-m halo (0-padded)
            int m = idx & 31, pos = idx >> 5;        // lanes: consecutive m
            int r = pos / 10, s = pos - r * 10;
            int gi = i0 + r - 1, gj = j0 + s - 1;
            float v = 0.f;
            if ((unsigned)gi < 64u && (unsigned)gj < 64u)
                v = feat[(((size_t)((b << 12) + (gi << 6) + gj)) << 6) + mb + m];
            fs[m * 121 + r * 12 + s] = v;            // stride-121: conflict-free
        }
        __syncthreads();

#pragma unroll 2
        for (int m = 0; m < 32; m++) {
            const float* fb = fs + m * 121 + li * 12 + lj;
            float f9[9];
#pragma unroll
            for (int r = 0; r < 3; r++)
#pragma unroll
                for (int s = 0; s < 3; s++) f9[r * 3 + s] = fb[r * 12 + s];
            const float* wrow = wet + (mb + m) * 1152;   // uniform -> s_load_dwordx8
#pragma unroll
            for (int rs = 0; rs < 9; rs++) {
                float f = f9[rs];
                const float* wr = wrow + rs * 128;
#pragma unroll
                for (int q = 0; q < 8; q++) acc[q] += f * wr[q];
            }
        }
        __syncthreads();                             // reads done before re-stage
    }

    // logits (+bias) -> fs[pix*66 + pp*33 + kk] (kk>=25 pad skipped)
#pragma unroll
    for (int q = 0; q < 8; q++) {
        int k = k0 + q;
        if (k < 25) fs[pix * 66 + pp * 33 + k] = acc[q] + be[p * 25 + k];
    }
    __syncthreads();

    if (t < 128) {                                   // softmax: thread = (pp, pixel)
        int sp = t >> 6, spx = t & 63;
        const float* lg = fs + spx * 66 + sp * 33;
        float sv[25], mx = -1e30f;
#pragma unroll
        for (int k = 0; k < 25; k++) { sv[k] = lg[k]; mx = fmaxf(mx, sv[k]); }
        float s = 0.f;
#pragma unroll
        for (int k = 0; k < 25; k++) { sv[k] = __expf(sv[k] - mx); s += sv[k]; }
        float inv = 1.f / s;
        int preal = (ph2 << 1) | sp;
        int pgl = ((i0 + (spx >> 3)) << 6) + j0 + (spx & 7);
        float* wp = wkout + (preal * 25) * 16384 + (b << 12) + pgl;
#pragma unroll
        for (int k = 0; k < 25; k++) wp[k * 16384] = sv[k] * inv;  // coalesced
    }
}

// ---------------- K3: gather + pixel rearrange ----------------
// grid 4096 = (b*64+i)*16 + cc(16 ch). 256 thr = 64 j x (2 p-pairs x 2 c-halves).
__global__ __launch_bounds__(256) void gather_kernel(
    const float* __restrict__ x, const float* __restrict__ ws,
    float* __restrict__ out) {
    __shared__ float xs[16 * 5 * 68];                // 21.76 KB
    int t = threadIdx.x;
    int blk = blockIdx.x;
    int cc = blk & 15;
    int bi = blk >> 4;
    int b = bi >> 6, i = bi & 63;
    int j = t & 63;
    int g = t >> 6;
    int ph = g >> 1, ch = g & 1;

    // coalesced wk loads: wk2[(p*25+k)*16384 + b*4096 + i*64 + j]
    float w0[25], w1[25];
    {
        const float* wp = ws + OFF_WK + (ph * 50) * 16384 + (b << 12) + (i << 6) + j;
#pragma unroll
        for (int k = 0; k < 25; k++) {
            w0[k] = wp[k * 16384];
            w1[k] = wp[(25 + k) * 16384];
        }
    }

    // div-free-ish staging: aligned 64-float row core + guarded zero pads.
    {
        int lane = t & 63, cd0 = t >> 6;             // (c,dy) pairs, 4 at a time
        for (int cd = cd0; cd < 80; cd += 4) {
            int c = cd / 5, dy = cd - c * 5;
            int gi = i - 2 + dy;
            float v = 0.f;
            if ((unsigned)gi < 64u)
                v = x[((b * 256 + (cc << 4) + c) << 12) + (gi << 6) + lane];
            float* row = xs + cd * 68;
            row[2 + lane] = v;
            if (lane < 2) row[lane] = 0.f;           // gj < 0 pad
            if (lane >= 62) row[lane + 4] = 0.f;     // gj >= 64 pad
        }
    }
    __syncthreads();

    for (int c2 = ch; c2 < 16; c2 += 2) {
        const float* xb = xs + (c2 * 5) * 68 + j;    // u = j+dx -> gj = j+dx-2
        float a0 = 0.f, a1 = 0.f;
#pragma unroll
        for (int dy = 0; dy < 5; dy++) {
#pragma unroll
            for (int dx = 0; dx < 5; dx++) {
                float xv = xb[dy * 68 + dx];
                int k = dy * 5 + dx;
                a0 += xv * w0[k];
                a1 += xv * w1[k];
            }
        }
        int c = (cc << 4) + c2;
        float2 o2 = make_float2(a0, a1);
        *(float2*)(out + (((b * 256 + c) << 12) + (i << 6) + j) * 4 + ph * 2) = o2;
    }
}

// ---------------- fallback: round-3 fused kernel (correct, slow) ----------------
__global__ __launch_bounds__(512) void carafe_fused(
    const float* __restrict__ x, const float* __restrict__ Wc,
    const float* __restrict__ bc, const float* __restrict__ We,
    const float* __restrict__ be, float* __restrict__ out) {
    __shared__ float xs[32 * 144];
    __shared__ float fw[6656];
    __shared__ float wst[3600];
    const int t = threadIdx.x;
    const int blk = blockIdx.x;
    const int b = blk >> 6, tile = blk & 63;
    const int i0 = (tile >> 3) << 3, j0 = (tile & 7) << 3;
    const int wid = t >> 6, pix = t & 63;
    const int li = pix >> 3, lj = pix & 7;
    float facc[13];
#pragma unroll
    for (int q = 0; q < 13; q++) facc[q] = 0.f;
    for (int cc = 0; cc < 8; cc++) {
        for (int idx = t; idx < 32 * 144; idx += 512) {
            int c = idx / 144, pos = idx - c * 144;
            int r = pos / 12, u = pos - r * 12;
            int gi = i0 + r - 2, gj = j0 + u - 2;
            float v = 0.f;
            if ((unsigned)gi < 64u && (unsigned)gj < 64u)
                v = x[(((b * 256 + cc * 32 + c) << 12) + (gi << 6) + gj)];
            xs[idx] = v;
        }
        __syncthreads();
#pragma unroll
        for (int q = 0; q < 13; q++) {
            int idx = q * 512 + t;
            if (idx < 6400) {
                int m = idx / 100, pos = idx - m * 100;
                int fi = pos / 10, fj = pos - fi * 10;
                int tp = (fi + 1) * 12 + fj + 1;
                const float* wr = Wc + m * 256 + cc * 32;
                float a = facc[q];
                for (int c = 0; c < 32; c++) a += xs[c * 144 + tp] * wr[c];
                facc[q] = a;
            }
        }
        __syncthreads();
    }
#pragma unroll
    for (int q = 0; q < 13; q++) {
        int idx = q * 512 + t;
        if (idx < 6400) {
            int m = idx / 100, pos = idx - m * 100;
            int fi = pos / 10, fj = pos - fi * 10;
            int gi = i0 + fi - 1, gj = j0 + fj - 1;
            float v = facc[q] + bc[m];
            v = v > 0.f ? v : 0.f;
            if ((unsigned)gi >= 64u || (unsigned)gj >= 64u) v = 0.f;
            fw[idx] = v;
        }
    }
    float acc[13];
#pragma unroll
    for (int q = 0; q < 13; q++) acc[q] = 0.f;
    for (int mb = 0; mb < 16; mb++) {
        for (int idx = t; idx < 3600; idx += 512) {
            int mm = idx / 900, rem = idx - mm * 900;
            int o = rem / 9, rs = rem - o * 9;
            wst[idx] = We[o * 576 + (mb * 4 + mm) * 9 + rs];
        }
        __syncthreads();
#pragma unroll
        for (int mm = 0; mm < 4; mm++) {
            const float* fb = fw + (mb * 4 + mm) * 100 + li * 10 + lj;
            float f9[9];
#pragma unroll
            for (int r = 0; r < 3; r++)
#pragma unroll
                for (int s = 0; s < 3; s++) f9[r * 3 + s] = fb[r * 10 + s];
#pragma unroll
            for (int q = 0; q < 13; q++) {
                int o = q * 8 + wid;
                if (o < 100) {
                    const float* wr = wst + mm * 900 + o * 9;
                    float a = acc[q];
#pragma unroll
                    for (int rs = 0; rs < 9; rs++) a += f9[rs] * wr[rs];
                    acc[q] = a;
                }
            }
        }
        __syncthreads();
    }
#pragma unroll
    for (int q = 0; q < 13; q++) {
        int o = q * 8 + wid;
        if (o < 100) fw[pix * 104 + o] = acc[q];
    }
    __syncthreads();
    float sv[25];
    float inv = 0.f;
    const int sp = t >> 6, spx = t & 63;
    const bool act = (t < 256);
    if (act) {
        float mx = -1e30f;
#pragma unroll
        for (int k = 0; k < 25; k++) {
            sv[k] = fw[spx * 104 + sp * 25 + k] + be[sp * 25 + k];
            mx = fmaxf(mx, sv[k]);
        }
        float s = 0.f;
#pragma unroll
        for (int k = 0; k < 25; k++) { sv[k] = __expf(sv[k] - mx); s += sv[k]; }
        inv = 1.f / s;
    }
    __syncthreads();
    if (act) {
#pragma unroll
        for (int k = 0; k < 25; k++) fw[spx * 104 + k * 4 + sp] = sv[k] * inv;
    }
    __syncthreads();
    float w[25][4];
    const float4* wp = (const float4*)(fw + pix * 104);
#pragma unroll
    for (int k = 0; k < 25; k++) {
        float4 ww = wp[k];
        w[k][0] = ww.x; w[k][1] = ww.y; w[k][2] = ww.z; w[k][3] = ww.w;
    }
    const int pgl = ((i0 + li) << 6) + (j0 + lj);
    for (int cc = 0; cc < 8; cc++) {
        for (int idx = t; idx < 32 * 144; idx += 512) {
            int c = idx / 144, pos = idx - c * 144;
            int r = pos / 12, u = pos - r * 12;
            int gi = i0 + r - 2, gj = j0 + u - 2;
            float v = 0.f;
            if ((unsigned)gi < 64u && (unsigned)gj < 64u)
                v = x[(((b * 256 + cc * 32 + c) << 12) + (gi << 6) + gj)];
            xs[idx] = v;
        }
        __syncthreads();
        for (int c8 = wid; c8 < 32; c8 += 8) {
            const float* xc = xs + c8 * 144 + li * 12 + lj;
            float a0 = 0.f, a1 = 0.f, a2 = 0.f, a3 = 0.f;
#pragma unroll
            for (int dy = 0; dy < 5; dy++) {
#pragma unroll
                for (int dx = 0; dx < 5; dx++) {
                    float xv = xc[dy * 12 + dx];
                    const int k = dy * 5 + dx;
                    a0 += xv * w[k][0];
                    a1 += xv * w[k][1];
                    a2 += xv * w[k][2];
                    a3 += xv * w[k][3];
                }
            }
            int c = cc * 32 + c8;
            float4 o4 = make_float4(a0, a1, a2, a3);
            *(float4*)(out + (((long long)(b * 256 + c)) << 14) + pgl * 4) = o4;
        }
        __syncthreads();
    }
}

extern "C" void kernel_launch(void* const* d_in, const int* in_sizes, int n_in,
                              void* d_out, int out_size, void* d_ws, size_t ws_size,
                              hipStream_t stream) {
    const float* x  = (const float*)d_in[0];
    const float* Wc = (const float*)d_in[1];
    const float* bc = (const float*)d_in[2];
    const float* We = (const float*)d_in[3];
    const float* be = (const float*)d_in[4];
    float* out = (float*)d_out;

    if (ws_size >= (size_t)WS_FLOATS * sizeof(float)) {
        float* ws = (float*)d_ws;
        prep_kernel<<<288, 256, 0, stream>>>(Wc, We, ws);
        compress_kernel<<<1024, 256, 0, stream>>>(x, bc, ws, ws + OFF_FEAT);
        enc_kernel<<<512, 512, 0, stream>>>(be, ws, ws + OFF_WK);
        gather_kernel<<<4096, 256, 0, stream>>>(x, ws, out);
    } else {
        carafe_fused<<<256, 512, 0, stream>>>(x, Wc, bc, We, be, out);
    }
}

// Round 9
// 177.406 us; speedup vs baseline: 1.4536x; 1.0952x over previous
//
#include <hip/hip_runtime.h>

// CARAFE++ (B=4, C=256, H=W=64, SCALE=2, K=5, G=1, MID=64, ENC_OUT=100). FP32 I/O.
// R14: 194.3us; compress fixed (lane=m, out of top-5); enc 49.2us @ VALU 51%,
//   occ 36%, conflicts 4.8M. Budget: VALU 25us + LDS ~25us SERIALIZED (joint
//   lgkmcnt for ds_read f9 + s_load weights -> lgkmcnt(0) drains per m-iter).
// R15: packed-FP32 (v_pk_fma_f32, VOP3P) in all three hot loops:
//   enc acc[8] -> f32x2 acc2[4] (halves FMA instr count: VALU 25 -> ~13us);
//   gather (a0,a1) pair -> f32x2 (shares xv splat); compress pairs share w.
//   Fallback if unpacked = identical scalar code -> zero regression risk.
//
// ws layout (float offsets):
#define OFF_FEAT 0              // feat [b][pix][m=64]             1,048,576 f
#define OFF_WET  1048576        // W_enc^T [m*9+rs][p*32+kk]          73,728 f
#define OFF_WCT  1122304        // W_comp^T [c][m]                    16,384 f
#define OFF_WK   1138688        // wk2 [p*25+k][b*4096+pix]        1,638,400 f
#define WS_FLOATS 2777088       // = 11,108,352 bytes

using f32x2 = __attribute__((ext_vector_type(2))) float;

// ---------------- prep: weight transposes ----------------
__global__ __launch_bounds__(256) void prep_kernel(
    const float* __restrict__ Wc, const float* __restrict__ We,
    float* __restrict__ ws) {
    int i = blockIdx.x * 256 + threadIdx.x;
    if (i < 16384) {                       // WcT[c*64+m] = Wc[m][c]
        int c = i >> 6, m = i & 63;
        ws[OFF_WCT + i] = Wc[m * 256 + c];
    }
    if (i < 73728) {                       // Wet[(m*9+rs)*128 + p*32 + kk]
        int mrs = i >> 7, rem = i & 127;
        int p = rem >> 5, kk = rem & 31;
        ws[OFF_WET + i] = (kk < 25) ? We[(p * 25 + kk) * 576 + mrs] : 0.f;
    }
}

// ---------------- K1: 1x1 compress conv + relu ----------------
// grid 1024 x 256 thr = 4 waves/block, wave = 4 px, lane = m.
// Per c: 1 coalesced w-load (VGPR) + 1 uniform float4 x-read (SGPR) + 2 pk-FMA.
__global__ __launch_bounds__(256) void compress_kernel(
    const float* __restrict__ x, const float* __restrict__ bc,
    const float* __restrict__ ws, float* __restrict__ feat) {
    int t = threadIdx.x;
    int lane = t & 63;                               // = m
    int px0 = __builtin_amdgcn_readfirstlane((blockIdx.x << 4) + ((t >> 6) << 2));
    int b = px0 >> 12, pl = px0 & 4095;
    const float* wct = ws + OFF_WCT;                 // [c][64 m]
    const float* xw = x + (((size_t)(b * 256)) << 12) + pl;   // wave-uniform
    f32x2 a01 = {0.f, 0.f}, a23 = {0.f, 0.f};
#pragma unroll 4
    for (int c = 0; c < 256; c++) {
        float w = wct[(c << 6) + lane];              // coalesced, L2-hot
        const float4 xv = *(const float4*)(xw + ((size_t)c << 12));  // uniform
        a01 += (f32x2){xv.x, xv.y} * w;
        a23 += (f32x2){xv.z, xv.w} * w;
    }
    float bv = bc[lane];
    float v0 = a01.x + bv, v1 = a01.y + bv, v2 = a23.x + bv, v3 = a23.y + bv;
    float* fp = feat + (((size_t)((b << 12) + pl)) << 6) + lane;  // [pix][m]
    fp[0]   = v0 > 0.f ? v0 : 0.f;                   // coalesced over m
    fp[64]  = v1 > 0.f ? v1 : 0.f;
    fp[128] = v2 > 0.f ? v2 : 0.f;
    fp[192] = v3 > 0.f ? v3 : 0.f;
}

// ---------------- K2: 3x3 enc conv + bias + softmax(25) ----------------
// grid 512 = (b x 8x8 tile) x 2 p-pairs. 512 thr = 64 px x (2p x 4 kg), q=8.
// Two-phase 32-m halo staging from feat[pix][m]; fs rows stride 121.
// FMA core packed: per rs 1 splat x 4 pk-FMA (acc2[4] = 8 q).
__global__ __launch_bounds__(512, 4) void enc_kernel(
    const float* __restrict__ be, const float* __restrict__ ws,
    float* __restrict__ wkout) {
    __shared__ float fs[4224];             // halo [32m][121] / logits [64px][2][33]
    int t = threadIdx.x;
    int blk = blockIdx.x;
    int tile = blk >> 1, ph2 = blk & 1;    // p-pair index
    int b = tile >> 6, t6 = tile & 63;
    int i0 = (t6 >> 3) << 3, j0 = (t6 & 7) << 3;
    int pix = t & 63;
    int li = pix >> 3, lj = pix & 7;
    int g = __builtin_amdgcn_readfirstlane(t >> 6);  // 0..7, wave-uniform
    int pp = g >> 2;                                 // p within pair
    int p = (ph2 << 1) | pp;
    int k0 = (g & 3) << 3;                           // kk = k0 + q, q<8 (pad >=25)
    const float* feat = ws + OFF_FEAT;               // [b][pix][64 m]
    const float* wet = ws + OFF_WET + p * 32 + k0;   // uniform, 32B-aligned

    f32x2 acc2[4];
#pragma unroll
    for (int q = 0; q < 4; q++) acc2[q] = (f32x2){0.f, 0.f};

    for (int phase = 0; phase < 2; phase++) {
        int mb = phase << 5;
        for (int idx = t; idx < 3200; idx += 512) {  // stage 32-m halo (0-padded)
            int m = idx & 31, pos = idx >> 5;        // lanes: consecutive m
            int r = pos / 10, s = pos - r * 10;
            int gi = i0 + r - 1, gj = j0 + s - 1;
            float v = 0.f;
            if ((unsigned)gi < 64u && (unsigned)gj < 64u)
                v = feat[(((size_t)((b << 12) + (gi << 6) + gj)) << 6) + mb + m];
            fs[m * 121 + r * 12 + s] = v;            // stride-121: conflict-free
        }
        __syncthreads();

#pragma unroll 2
        for (int m = 0; m < 32; m++) {
            const float* fb = fs + m * 121 + li * 12 + lj;
            float f9[9];
#pragma unroll
            for (int r = 0; r < 3; r++)
#pragma unroll
                for (int s = 0; s < 3; s++) f9[r * 3 + s] = fb[r * 12 + s];
            const float* wrow = wet + (mb + m) * 1152;   // uniform -> s_load_dwordx8
#pragma unroll
            for (int rs = 0; rs < 9; rs++) {
                float f = f9[rs];
                const f32x2* w2 = (const f32x2*)(wrow + rs * 128);  // 8B-aligned
#pragma unroll
                for (int q = 0; q < 4; q++) acc2[q] += f * w2[q];
            }
        }
        __syncthreads();                             // reads done before re-stage
    }

    // logits (+bias) -> fs[pix*66 + pp*33 + kk] (kk>=25 pad skipped)
#pragma unroll
    for (int q = 0; q < 8; q++) {
        int k = k0 + q;
        float aq = (q & 1) ? acc2[q >> 1].y : acc2[q >> 1].x;
        if (k < 25) fs[pix * 66 + pp * 33 + k] = aq + be[p * 25 + k];
    }
    __syncthreads();

    if (t < 128) {                                   // softmax: thread = (pp, pixel)
        int sp = t >> 6, spx = t & 63;
        const float* lg = fs + spx * 66 + sp * 33;
        float sv[25], mx = -1e30f;
#pragma unroll
        for (int k = 0; k < 25; k++) { sv[k] = lg[k]; mx = fmaxf(mx, sv[k]); }
        float s = 0.f;
#pragma unroll
        for (int k = 0; k < 25; k++) { sv[k] = __expf(sv[k] - mx); s += sv[k]; }
        float inv = 1.f / s;
        int preal = (ph2 << 1) | sp;
        int pgl = ((i0 + (spx >> 3)) << 6) + j0 + (spx & 7);
        float* wp = wkout + (preal * 25) * 16384 + (b << 12) + pgl;
#pragma unroll
        for (int k = 0; k < 25; k++) wp[k * 16384] = sv[k] * inv;  // coalesced
    }
}

// ---------------- K3: gather + pixel rearrange ----------------
// grid 4096 = (b*64+i)*16 + cc(16 ch). 256 thr = 64 j x (2 p-pairs x 2 c-halves).
// Inner: per xv 1 pk-FMA (p-pair packed in f32x2 w01[25]).
__global__ __launch_bounds__(256) void gather_kernel(
    const float* __restrict__ x, const float* __restrict__ ws,
    float* __restrict__ out) {
    __shared__ float xs[16 * 5 * 68];                // 21.76 KB
    int t = threadIdx.x;
    int blk = blockIdx.x;
    int cc = blk & 15;
    int bi = blk >> 4;
    int b = bi >> 6, i = bi & 63;
    int j = t & 63;
    int g = t >> 6;
    int ph = g >> 1, ch = g & 1;

    // coalesced wk loads: wk2[(p*25+k)*16384 + b*4096 + i*64 + j]
    f32x2 w01[25];
    {
        const float* wp = ws + OFF_WK + (ph * 50) * 16384 + (b << 12) + (i << 6) + j;
#pragma unroll
        for (int k = 0; k < 25; k++) {
            w01[k].x = wp[k * 16384];
            w01[k].y = wp[(25 + k) * 16384];
        }
    }

    // div-free-ish staging: aligned 64-float row core + guarded zero pads.
    {
        int lane = t & 63, cd0 = t >> 6;             // (c,dy) pairs, 4 at a time
        for (int cd = cd0; cd < 80; cd += 4) {
            int c = cd / 5, dy = cd - c * 5;
            int gi = i - 2 + dy;
            float v = 0.f;
            if ((unsigned)gi < 64u)
                v = x[((b * 256 + (cc << 4) + c) << 12) + (gi << 6) + lane];
            float* row = xs + cd * 68;
            row[2 + lane] = v;
            if (lane < 2) row[lane] = 0.f;           // gj < 0 pad
            if (lane >= 62) row[lane + 4] = 0.f;     // gj >= 64 pad
        }
    }
    __syncthreads();

    for (int c2 = ch; c2 < 16; c2 += 2) {
        const float* xb = xs + (c2 * 5) * 68 + j;    // u = j+dx -> gj = j+dx-2
        f32x2 a2 = {0.f, 0.f};
#pragma unroll
        for (int dy = 0; dy < 5; dy++) {
#pragma unroll
            for (int dx = 0; dx < 5; dx++) {
                float xv = xb[dy * 68 + dx];
                a2 += xv * w01[dy * 5 + dx];
            }
        }
        int c = (cc << 4) + c2;
        *(float2*)(out + (((b * 256 + c) << 12) + (i << 6) + j) * 4 + ph * 2) =
            make_float2(a2.x, a2.y);
    }
}

// ---------------- fallback: round-3 fused kernel (correct, slow) ----------------
__global__ __launch_bounds__(512) void carafe_fused(
    const float* __restrict__ x, const float* __restrict__ Wc,
    const float* __restrict__ bc, const float* __restrict__ We,
    const float* __restrict__ be, float* __restrict__ out) {
    __shared__ float xs[32 * 144];
    __shared__ float fw[6656];
    __shared__ float wst[3600];
    const int t = threadIdx.x;
    const int blk = blockIdx.x;
    const int b = blk >> 6, tile = blk & 63;
    const int i0 = (tile >> 3) << 3, j0 = (tile & 7) << 3;
    const int wid = t >> 6, pix = t & 63;
    const int li = pix >> 3, lj = pix & 7;
    float facc[13];
#pragma unroll
    for (int q = 0; q < 13; q++) facc[q] = 0.f;
    for (int cc = 0; cc < 8; cc++) {
        for (int idx = t; idx < 32 * 144; idx += 512) {
            int c = idx / 144, pos = idx - c * 144;
            int r = pos / 12, u = pos - r * 12;
            int gi = i0 + r - 2, gj = j0 + u - 2;
            float v = 0.f;
            if ((unsigned)gi < 64u && (unsigned)gj < 64u)
                v = x[(((b * 256 + cc * 32 + c) << 12) + (gi << 6) + gj)];
            xs[idx] = v;
        }
        __syncthreads();
#pragma unroll
        for (int q = 0; q < 13; q++) {
            int idx = q * 512 + t;
            if (idx < 6400) {
                int m = idx / 100, pos = idx - m * 100;
                int fi = pos / 10, fj = pos - fi * 10;
                int tp = (fi + 1) * 12 + fj + 1;
                const float* wr = Wc + m * 256 + cc * 32;
                float a = facc[q];
                for (int c = 0; c < 32; c++) a += xs[c * 144 + tp] * wr[c];
                facc[q] = a;
            }
        }
        __syncthreads();
    }
#pragma unroll
    for (int q = 0; q < 13; q++) {
        int idx = q * 512 + t;
        if (idx < 6400) {
            int m = idx / 100, pos = idx - m * 100;
            int fi = pos / 10, fj = pos - fi * 10;
            int gi = i0 + fi - 1, gj = j0 + fj - 1;
            float v = facc[q] + bc[m];
            v = v > 0.f ? v : 0.f;
            if ((unsigned)gi >= 64u || (unsigned)gj >= 64u) v = 0.f;
            fw[idx] = v;
        }
    }
    float acc[13];
#pragma unroll
    for (int q = 0; q < 13; q++) acc[q] = 0.f;
    for (int mb = 0; mb < 16; mb++) {
        for (int idx = t; idx < 3600; idx += 512) {
            int mm = idx / 900, rem = idx - mm * 900;
            int o = rem / 9, rs = rem - o * 9;
            wst[idx] = We[o * 576 + (mb * 4 + mm) * 9 + rs];
        }
        __syncthreads();
#pragma unroll
        for (int mm = 0; mm < 4; mm++) {
            const float* fb = fw + (mb * 4 + mm) * 100 + li * 10 + lj;
            float f9[9];
#pragma unroll
            for (int r = 0; r < 3; r++)
#pragma unroll
                for (int s = 0; s < 3; s++) f9[r * 3 + s] = fb[r * 10 + s];
#pragma unroll
            for (int q = 0; q < 13; q++) {
                int o = q * 8 + wid;
                if (o < 100) {
                    const float* wr = wst + mm * 900 + o * 9;
                    float a = acc[q];
#pragma unroll
                    for (int rs = 0; rs < 9; rs++) a += f9[rs] * wr[rs];
                    acc[q] = a;
                }
            }
        }
        __syncthreads();
    }
#pragma unroll
    for (int q = 0; q < 13; q++) {
        int o = q * 8 + wid;
        if (o < 100) fw[pix * 104 + o] = acc[q];
    }
    __syncthreads();
    float sv[25];
    float inv = 0.f;
    const int sp = t >> 6, spx = t & 63;
    const bool act = (t < 256);
    if (act) {
        float mx = -1e30f;
#pragma unroll
        for (int k = 0; k < 25; k++) {
            sv[k] = fw[spx * 104 + sp * 25 + k] + be[sp * 25 + k];
            mx = fmaxf(mx, sv[k]);
        }
        float s = 0.f;
#pragma unroll
        for (int k = 0; k < 25; k++) { sv[k] = __expf(sv[k] - mx); s += sv[k]; }
        inv = 1.f / s;
    }
    __syncthreads();
    if (act) {
#pragma unroll
        for (int k = 0; k < 25; k++) fw[spx * 104 + k * 4 + sp] = sv[k] * inv;
    }
    __syncthreads();
    float w[25][4];
    const float4* wp = (const float4*)(fw + pix * 104);
#pragma unroll
    for (int k = 0; k < 25; k++) {
        float4 ww = wp[k];
        w[k][0] = ww.x; w[k][1] = ww.y; w[k][2] = ww.z; w[k][3] = ww.w;
    }
    const int pgl = ((i0 + li) << 6) + (j0 + lj);
    for (int cc = 0; cc < 8; cc++) {
        for (int idx = t; idx < 32 * 144; idx += 512) {
            int c = idx / 144, pos = idx - c * 144;
            int r = pos / 12, u = pos - r * 12;
            int gi = i0 + r - 2, gj = j0 + u - 2;
            float v = 0.f;
            if ((unsigned)gi < 64u && (unsigned)gj < 64u)
                v = x[(((b * 256 + cc * 32 + c) << 12) + (gi << 6) + gj)];
            xs[idx] = v;
        }
        __syncthreads();
        for (int c8 = wid; c8 < 32; c8 += 8) {
            const float* xc = xs + c8 * 144 + li * 12 + lj;
            float a0 = 0.f, a1 = 0.f, a2 = 0.f, a3 = 0.f;
#pragma unroll
            for (int dy = 0; dy < 5; dy++) {
#pragma unroll
                for (int dx = 0; dx < 5; dx++) {
                    float xv = xc[dy * 12 + dx];
                    const int k = dy * 5 + dx;
                    a0 += xv * w[k][0];
                    a1 += xv * w[k][1];
                    a2 += xv * w[k][2];
                    a3 += xv * w[k][3];
                }
            }
            int c = cc * 32 + c8;
            float4 o4 = make_float4(a0, a1, a2, a3);
            *(float4*)(out + (((long long)(b * 256 + c)) << 14) + pgl * 4) = o4;
        }
        __syncthreads();
    }
}

extern "C" void kernel_launch(void* const* d_in, const int* in_sizes, int n_in,
                              void* d_out, int out_size, void* d_ws, size_t ws_size,
                              hipStream_t stream) {
    const float* x  = (const float*)d_in[0];
    const float* Wc = (const float*)d_in[1];
    const float* bc = (const float*)d_in[2];
    const float* We = (const float*)d_in[3];
    const float* be = (const float*)d_in[4];
    float* out = (float*)d_out;

    if (ws_size >= (size_t)WS_FLOATS * sizeof(float)) {
        float* ws = (float*)d_ws;
        prep_kernel<<<288, 256, 0, stream>>>(Wc, We, ws);
        compress_kernel<<<1024, 256, 0, stream>>>(x, bc, ws, ws + OFF_FEAT);
        enc_kernel<<<512, 512, 0, stream>>>(be, ws, ws + OFF_WK);
        gather_kernel<<<4096, 256, 0, stream>>>(x, ws, out);
    } else {
        carafe_fused<<<256, 512, 0, stream>>>(x, Wc, bc, We, be, out);
    }
}